// Round 6
// baseline (935.275 us; speedup 1.0000x reference)
//
#include <hip/hip_runtime.h>

typedef unsigned short u16;
typedef unsigned int u32;
typedef __attribute__((ext_vector_type(8))) __bf16 bf16x8;
typedef __attribute__((ext_vector_type(4))) float f32x4;
typedef __attribute__((ext_vector_type(4))) u32 u32x4;
typedef __attribute__((ext_vector_type(2))) u32 u32x2;

#define HW 16384
#define C 128
#define NB 16
#define LSTR 136   // u16/row: 272B row stride rotates banks by 4/row — do NOT set to 128

__device__ __forceinline__ u16 f2bf(float f) {
    __bf16 h = (__bf16)f;
    union { __bf16 h; u16 u; } c; c.h = h; return c.u;
}

// load all 8 weight fragments for one MFMA pass (bf16, k-contiguous rows)
__device__ __forceinline__ void load_af(
    const u16* __restrict__ W, bf16x8 (&af)[2][4], int wave, int m_lo, int quad)
{
    #pragma unroll
    for (int mt = 0; mt < 2; ++mt)
        #pragma unroll
        for (int ks = 0; ks < 4; ++ks) {
            int m = wave * 32 + mt * 16 + m_lo;
            af[mt][ks] = *(const bf16x8*)(W + (size_t)m * 128 + ks * 32 + quad * 8);
        }
}

// 64 MFMA over a staged 128x128 LDS tile (XOR-swizzled) with pre-loaded weights.
// Swapped operands: a = X-fragment (n rows), b = W-fragment.
// acc[mt][nt][r] -> channel m = wave*32+mt*16+m_lo, px n = nt*16+quad*4+r.
__device__ __forceinline__ void mfma_tile2(
    const bf16x8 (&af)[2][4], const u16* lds,
    f32x4 (&acc)[2][8], int m_lo, int quad)
{
    #pragma unroll
    for (int mt = 0; mt < 2; ++mt)
        #pragma unroll
        for (int nt = 0; nt < 8; ++nt) {
            f32x4 z = {0.f, 0.f, 0.f, 0.f};
            acc[mt][nt] = z;
        }
    #pragma unroll
    for (int ks = 0; ks < 4; ++ks) {
        #pragma unroll
        for (int nt = 0; nt < 8; ++nt) {
            int n  = nt * 16 + m_lo;
            int cs = (ks * 4 + quad) ^ ((n >> 2) & 7);
            bf16x8 bfrag = *(const bf16x8*)(lds + n * LSTR + cs * 8);
            acc[0][nt] = __builtin_amdgcn_mfma_f32_16x16x32_bf16(bfrag, af[0][ks], acc[0][nt], 0, 0, 0);
            acc[1][nt] = __builtin_amdgcn_mfma_f32_16x16x32_bf16(bfrag, af[1][ks], acc[1][nt], 0, 0, 0);
        }
    }
}

// stage one image row of X (fp32 [128ch][128px]) -> bf16 XOR-swizzled tile [px][ch]
__device__ __forceinline__ void stage_row(
    const float* __restrict__ Xb, int rowIdx, u16* xt, int tid)
{
    f32x4 v[2][8];
    #pragma unroll
    for (int r = 0; r < 2; ++r) {
        int idx = tid + 256 * r;
        int n4  = idx & 31;
        int kc  = idx >> 5;
        const float* src = Xb + (size_t)(kc * 8) * HW + rowIdx * 128 + n4 * 4;
        #pragma unroll
        for (int j = 0; j < 8; ++j) v[r][j] = *(const f32x4*)(src + (size_t)j * HW);
    }
    #pragma unroll
    for (int r = 0; r < 2; ++r) {
        int idx = tid + 256 * r;
        int n4  = idx & 31;
        int kc  = idx >> 5;
        #pragma unroll
        for (int t = 0; t < 4; ++t) {
            union { u16 u[8]; u32x4 q; } e;
            #pragma unroll
            for (int j = 0; j < 8; ++j) e.u[j] = f2bf(v[r][j][t]);
            int row = n4 * 4 + t;
            int cs  = kc ^ (n4 & 7);
            *(u32x4*)(xt + row * LSTR + cs * 8) = e.q;
        }
    }
}

// fold one conv-row (acc + conv bias) into the running dwconv accumulator.
// Horizontal neighbors via 2 shfls (px layout: nt*16+quad*4+r); rm masks
// out-of-image rows (reference zero-pads).
__device__ __forceinline__ void fold_dw(
    const f32x4 (&acc)[2][8], float (&oacc)[2][8][4],
    const float (&cbias)[2], const float (&dww)[2][9],
    int dr, float rm, int lane, int quad)
{
    #pragma unroll
    for (int mt = 0; mt < 2; ++mt) {
        float cbm = cbias[mt];
        float w0 = dww[mt][dr * 3 + 0], w1 = dww[mt][dr * 3 + 1], w2 = dww[mt][dr * 3 + 2];
        #pragma unroll
        for (int nt = 0; nt < 8; ++nt) {
            float c0 = acc[mt][nt][0] + cbm;
            float c1 = acc[mt][nt][1] + cbm;
            float c2 = acc[mt][nt][2] + cbm;
            float c3 = acc[mt][nt][3] + cbm;
            // left neighbor: quad>0 -> lane-16 same nt r3; quad==0 -> lane+48 nt-1 r3
            float xl = (quad == 3) ? (acc[mt][(nt + 7) & 7][3] + cbm) : c3;
            float xr = (quad == 0) ? (acc[mt][(nt + 1) & 7][0] + cbm) : c0;
            float lv = __shfl(xl, (lane + 48) & 63);
            float rv = __shfl(xr, (lane + 16) & 63);
            if (nt == 0) lv = (quad == 0) ? 0.f : lv;   // image left edge
            if (nt == 7) rv = (quad == 3) ? 0.f : rv;   // image right edge
            float g0 = lv * rm, g1 = c0 * rm, g2 = c1 * rm, g3 = c2 * rm, g4 = c3 * rm, g5 = rv * rm;
            oacc[mt][nt][0] += w0 * g0 + w1 * g1 + w2 * g2;
            oacc[mt][nt][1] += w0 * g1 + w1 * g2 + w2 * g3;
            oacc[mt][nt][2] += w0 * g2 + w1 * g3 + w2 * g4;
            oacc[mt][nt][3] += w0 * g3 + w1 * g4 + w2 * g5;
        }
    }
}

// ---- K0: pre-convert conv1x1 weights to bf16 (once) ----
__global__ __launch_bounds__(256) void k_wcvt(
    const float* __restrict__ qw, const float* __restrict__ kw,
    const float* __restrict__ vw, u16* __restrict__ wbf)
{
    int m = blockIdx.x;
    const float* src = m == 0 ? qw : (m == 1 ? kw : vw);
    u16* dst = wbf + (size_t)m * 16384;
    #pragma unroll
    for (int i = 0; i < 16; ++i) {
        int idx = threadIdx.x + 256 * i;
        f32x4 v = *(const f32x4*)(src + idx * 4);
        u32x2 p;
        p.x = (u32)f2bf(v[0]) | ((u32)f2bf(v[1]) << 16);
        p.y = (u32)f2bf(v[2]) | ((u32)f2bf(v[3]) << 16);
        *(u32x2*)(dst + idx * 4) = p;
    }
}

// ---- K1: fused conv1x1 + depthwise3x3 for q,k. 3-row halo recomputed via MFMA;
// dwconv folded in registers; writes FINAL q,k planes + norm2 atomics.
// Eliminates the raw-plane write + k_dw_qk read/rewrite (268 MB HBM).
__global__ __launch_bounds__(256) void k_qk_fused(
    const float* __restrict__ x, const u16* __restrict__ wbf,
    const float* __restrict__ qbi, const float* __restrict__ kbi,
    const float* __restrict__ qdw, const float* __restrict__ qdb,
    const float* __restrict__ kdw, const float* __restrict__ kdb,
    u16* __restrict__ qpl, u16* __restrict__ kpl, float* __restrict__ norm2)
{
    __shared__ __align__(16) u16 xs[3][128 * LSTR];   // 104 KB
    const int tid  = threadIdx.x;
    const int lane = tid & 63;
    const int wave = tid >> 6;
    const int m_lo = lane & 15;
    const int quad = lane >> 4;
    const int b = blockIdx.z;
    const int r = blockIdx.x;            // image row
    const int n0 = r * 128;
    const float* Xb = x + (size_t)b * C * HW;

    int rs[3] = { r > 0 ? r - 1 : 0, r, r < 127 ? r + 1 : 127 };
    float rmask[3] = { r > 0 ? 1.f : 0.f, 1.f, r < 127 ? 1.f : 0.f };

    stage_row(Xb, rs[0], xs[0], tid);
    stage_row(Xb, rs[1], xs[1], tid);
    stage_row(Xb, rs[2], xs[2], tid);
    __syncthreads();

    #pragma unroll 1
    for (int sp = 0; sp < 2; ++sp) {
        const u16* W      = wbf + sp * 16384;
        const float* cbp  = sp ? kbi : qbi;
        const float* dwWp = sp ? kdw : qdw;
        const float* dwBp = sp ? kdb : qdb;
        u16* Y = (sp ? kpl : qpl) + (size_t)b * C * HW;

        bf16x8 af[2][4];
        load_af(W, af, wave, m_lo, quad);
        float cbias[2], dww[2][9];
        #pragma unroll
        for (int mt = 0; mt < 2; ++mt) {
            int m = wave * 32 + mt * 16 + m_lo;
            cbias[mt] = cbp[m];
            #pragma unroll
            for (int j = 0; j < 9; ++j) dww[mt][j] = dwWp[m * 9 + j];
        }

        float oacc[2][8][4];
        #pragma unroll
        for (int mt = 0; mt < 2; ++mt)
            #pragma unroll
            for (int nt = 0; nt < 8; ++nt)
                #pragma unroll
                for (int rr = 0; rr < 4; ++rr) oacc[mt][nt][rr] = 0.f;

        f32x4 acc[2][8];
        #pragma unroll
        for (int dr = 0; dr < 3; ++dr) {
            mfma_tile2(af, xs[dr], acc, m_lo, quad);
            fold_dw(acc, oacc, cbias, dww, dr, rmask[dr], lane, quad);
        }

        // finalize: +dw bias, ssq, packed stores, norm2 atomics
        #pragma unroll
        for (int mt = 0; mt < 2; ++mt) {
            int m = wave * 32 + mt * 16 + m_lo;
            float b2 = dwBp[m];
            u16* rowp = Y + (size_t)m * HW + n0 + quad * 4;
            float sq = 0.f;
            #pragma unroll
            for (int nt = 0; nt < 8; ++nt) {
                float o0 = oacc[mt][nt][0] + b2;
                float o1 = oacc[mt][nt][1] + b2;
                float o2 = oacc[mt][nt][2] + b2;
                float o3 = oacc[mt][nt][3] + b2;
                sq += o0 * o0 + o1 * o1 + o2 * o2 + o3 * o3;
                u32x2 pr;
                pr.x = (u32)f2bf(o0) | ((u32)f2bf(o1) << 16);
                pr.y = (u32)f2bf(o2) | ((u32)f2bf(o3) << 16);
                *(u32x2*)(rowp + nt * 16) = pr;
            }
            sq += __shfl_xor(sq, 16);
            sq += __shfl_xor(sq, 32);
            if (quad == 0) atomicAdd(&norm2[sp * (NB * C) + b * C + m], sq);
        }
    }
}

// ---- K3: Gram, split-K=32 x split-N=2 (1024 blocks), fp32 atomics into G ----
__global__ __launch_bounds__(256) void k_gram(
    const u16* __restrict__ q, const u16* __restrict__ k, float* __restrict__ G)
{
    int kz = blockIdx.x, nz = blockIdx.y, b = blockIdx.z;
    const u16* qb = q + (size_t)b * C * HW;
    const u16* kb = k + (size_t)b * C * HW;
    int lane = threadIdx.x & 63, wave = threadIdx.x >> 6;
    int m_lo = lane & 15, quad = lane >> 4;
    f32x4 acc[2][4];
    #pragma unroll
    for (int mt = 0; mt < 2; ++mt)
        #pragma unroll
        for (int nt = 0; nt < 4; ++nt) {
            f32x4 z = {0.f, 0.f, 0.f, 0.f};
            acc[mt][nt] = z;
        }
    #pragma unroll 4
    for (int step = 0; step < 16; ++step) {
        int kk = kz * 512 + step * 32 + quad * 8;
        bf16x8 a0 = *(const bf16x8*)(qb + (size_t)(wave * 32 + m_lo) * HW + kk);
        bf16x8 a1 = *(const bf16x8*)(qb + (size_t)(wave * 32 + 16 + m_lo) * HW + kk);
        #pragma unroll
        for (int nt = 0; nt < 4; ++nt) {
            bf16x8 bf = *(const bf16x8*)(kb + (size_t)(nz * 64 + nt * 16 + m_lo) * HW + kk);
            acc[0][nt] = __builtin_amdgcn_mfma_f32_16x16x32_bf16(a0, bf, acc[0][nt], 0, 0, 0);
            acc[1][nt] = __builtin_amdgcn_mfma_f32_16x16x32_bf16(a1, bf, acc[1][nt], 0, 0, 0);
        }
    }
    float* Gb = G + (size_t)b * C * C;
    #pragma unroll
    for (int mt = 0; mt < 2; ++mt)
        #pragma unroll
        for (int nt = 0; nt < 4; ++nt)
            #pragma unroll
            for (int rr = 0; rr < 4; ++rr) {
                int m = wave * 32 + mt * 16 + quad * 4 + rr;
                int n = nz * 64 + nt * 16 + m_lo;
                atomicAdd(&Gb[m * C + n], acc[mt][nt][rr]);
            }
}

// ---- K4a: normalize + row softmax in-place on G ----
__global__ __launch_bounds__(128) void k_softmax(float* __restrict__ G, const float* __restrict__ norm2)
{
    __shared__ float red[128];
    int c = blockIdx.x, b = blockIdx.y, d = threadIdx.x;
    float* row = G + ((size_t)b * C + c) * C;
    float nq = fmaxf(sqrtf(norm2[b * C + c]), 1e-12f);
    float nk = fmaxf(sqrtf(norm2[NB * C + b * C + d]), 1e-12f);
    float sv = row[d] / (nq * nk);
    red[d] = sv; __syncthreads();
    for (int off = 64; off > 0; off >>= 1) {
        if (d < off) red[d] = fmaxf(red[d], red[d + off]);
        __syncthreads();
    }
    float mx = red[0]; __syncthreads();
    float e = __expf(sv - mx);
    red[d] = e; __syncthreads();
    for (int off = 64; off > 0; off >>= 1) {
        if (d < off) red[d] += red[d + off];
        __syncthreads();
    }
    row[d] = e / red[0];
}

// ---- K4b: M_b = aw @ A_b (bf16 out) ----
__global__ __launch_bounds__(256) void k_mproj(
    const float* __restrict__ G, const float* __restrict__ aw, u16* __restrict__ M)
{
    __shared__ float As[128 * 16];
    int b = blockIdx.y, d0 = blockIdx.x * 16, tid = threadIdx.x;
    const float* A = G + (size_t)b * C * C;
    #pragma unroll
    for (int i = 0; i < 8; ++i) {
        int idx = tid + 256 * i;
        int cc = idx >> 4, dd = idx & 15;
        As[idx] = A[cc * C + d0 + dd];
    }
    __syncthreads();
    #pragma unroll
    for (int i = 0; i < 8; ++i) {
        int idx = tid + 256 * i;
        int oo = idx >> 4, dd = idx & 15;
        float s = 0.f;
        for (int cc = 0; cc < 128; ++cc)
            s += aw[oo * C + cc] * As[cc * 16 + dd];
        M[((size_t)b * C + oo) * C + d0 + dd] = f2bf(s);
    }
}

// ---- K5: fused conv1x1(vw) + dwconv3 + M-multiply. x is never written; the
// v plane round-trip (268 MB) is eliminated. dwv scatter-written into the
// B-operand tile (reuses xs[0]) for the final MFMA.
__global__ __launch_bounds__(256) void k_out_fused(
    const u16* __restrict__ M, const float* __restrict__ x, const u16* __restrict__ wbf,
    const float* __restrict__ vbi, const float* __restrict__ vdw, const float* __restrict__ vdb,
    const float* __restrict__ ab, float* __restrict__ out)
{
    __shared__ __align__(16) u16 xs[3][128 * LSTR];
    const int tid  = threadIdx.x;
    const int lane = tid & 63;
    const int wave = tid >> 6;
    const int m_lo = lane & 15;
    const int quad = lane >> 4;
    const int b = blockIdx.z;
    const int r = blockIdx.x;
    const int n0 = r * 128;
    const float* Xb = x + (size_t)b * C * HW;

    int rs[3] = { r > 0 ? r - 1 : 0, r, r < 127 ? r + 1 : 127 };
    float rmask[3] = { r > 0 ? 1.f : 0.f, 1.f, r < 127 ? 1.f : 0.f };

    stage_row(Xb, rs[0], xs[0], tid);
    stage_row(Xb, rs[1], xs[1], tid);
    stage_row(Xb, rs[2], xs[2], tid);
    __syncthreads();

    const u16* wv = wbf + 32768;
    bf16x8 af[2][4];
    load_af(wv, af, wave, m_lo, quad);
    float cbias[2], dww[2][9];
    #pragma unroll
    for (int mt = 0; mt < 2; ++mt) {
        int m = wave * 32 + mt * 16 + m_lo;
        cbias[mt] = vbi[m];
        #pragma unroll
        for (int j = 0; j < 9; ++j) dww[mt][j] = vdw[m * 9 + j];
    }

    float oacc[2][8][4];
    #pragma unroll
    for (int mt = 0; mt < 2; ++mt)
        #pragma unroll
        for (int nt = 0; nt < 8; ++nt)
            #pragma unroll
            for (int rr = 0; rr < 4; ++rr) oacc[mt][nt][rr] = 0.f;

    f32x4 acc[2][8];
    #pragma unroll
    for (int dr = 0; dr < 3; ++dr) {
        mfma_tile2(af, xs[dr], acc, m_lo, quad);
        fold_dw(acc, oacc, cbias, dww, dr, rmask[dr], lane, quad);
    }
    __syncthreads();   // all xs reads done; xs[0] reusable

    // scatter dwv (+vdb) bf16 into B-operand layout: [px][ch] XOR-swizzled
    u16* bt = xs[0];
    #pragma unroll
    for (int mt = 0; mt < 2; ++mt) {
        int m = wave * 32 + mt * 16 + m_lo;
        int khi = m >> 3, klo = m & 7;
        float b2 = vdb[m];
        #pragma unroll
        for (int nt = 0; nt < 8; ++nt) {
            int cs = khi ^ ((nt * 4 + quad) & 7);
            #pragma unroll
            for (int rr = 0; rr < 4; ++rr) {
                int px = nt * 16 + quad * 4 + rr;
                bt[px * LSTR + cs * 8 + klo] = f2bf(oacc[mt][nt][rr] + b2);
            }
        }
    }
    __syncthreads();

    bf16x8 afm[2][4];
    load_af(M + (size_t)b * C * C, afm, wave, m_lo, quad);
    mfma_tile2(afm, bt, acc, m_lo, quad);

    float* Ob = out + (size_t)b * C * HW;
    #pragma unroll
    for (int mt = 0; mt < 2; ++mt) {
        int m = wave * 32 + mt * 16 + m_lo;
        float bm = ab[m];
        float* rowp = Ob + (size_t)m * HW + n0 + quad * 4;
        #pragma unroll
        for (int nt = 0; nt < 8; ++nt) {
            f32x4 o = acc[mt][nt];
            o[0] += bm; o[1] += bm; o[2] += bm; o[3] += bm;
            *(f32x4*)(rowp + nt * 16) = o;
        }
    }
}

extern "C" void kernel_launch(void* const* d_in, const int* in_sizes, int n_in,
                              void* d_out, int out_size, void* d_ws, size_t ws_size,
                              hipStream_t stream)
{
    const float* x   = (const float*)d_in[0];   // never written in this pipeline
    const float* qw  = (const float*)d_in[1];
    const float* qbi = (const float*)d_in[2];
    const float* qdw = (const float*)d_in[3];
    const float* qdb = (const float*)d_in[4];
    const float* kw  = (const float*)d_in[5];
    const float* kbi = (const float*)d_in[6];
    const float* kdw = (const float*)d_in[7];
    const float* kdb = (const float*)d_in[8];
    const float* vw  = (const float*)d_in[9];
    const float* vbi = (const float*)d_in[10];
    const float* vdw = (const float*)d_in[11];
    const float* vdb = (const float*)d_in[12];
    const float* aw  = (const float*)d_in[13];
    const float* ab  = (const float*)d_in[14];

    u16* qpl = (u16*)d_out;
    u16* kpl = qpl + (size_t)NB * C * HW;

    float* G     = (float*)d_ws;               // 1 MiB
    float* norm2 = G + (size_t)NB * C * C;     // 16 KiB (zeroed with G)
    u16*   M     = (u16*)(norm2 + 2 * NB * C); // 0.5 MiB
    u16*   wbf   = M + (size_t)NB * C * C;     // 96 KiB (bf16 qw,kw,vw)

    hipMemsetAsync(G, 0, ((size_t)NB * C * C + 2 * NB * C) * sizeof(float), stream);

    k_wcvt<<<dim3(3), 256, 0, stream>>>(qw, kw, vw, wbf);
    k_qk_fused<<<dim3(128, 1, NB), 256, 0, stream>>>(
        x, wbf, qbi, kbi, qdw, qdb, kdw, kdb, qpl, kpl, norm2);
    k_gram<<<dim3(32, 2, NB), 256, 0, stream>>>(qpl, kpl, G);
    k_softmax<<<dim3(C, NB), 128, 0, stream>>>(G, norm2);
    k_mproj<<<dim3(8, NB), 256, 0, stream>>>(G, aw, M);
    k_out_fused<<<dim3(128, 1, NB), 256, 0, stream>>>(M, x, wbf, vbi, vdw, vdb, ab, (float*)d_out);
}